// Round 16
// baseline (479.257 us; speedup 1.0000x reference)
//
#include <hip/hip_runtime.h>
#include <hip/hip_bf16.h>

// BRITS-style RNN (B=4096, T=256, D=36, H=64) on gfx950.
// R16: R15 + gamma cross-wave race FIX. R11-R15 had each S-wave write gamma
// only for its own 4 rows in S-P2, then read comb A-frags spanning ALL 16 rows
// (other waves' gamma) in the same phase with no sync - a latent race that
// passed only because the 4 S-waves run identical-length code in near-lockstep.
// Fix: all 27 precompute MFMAs are already computed redundantly (identically)
// by every S-wave, so each wave now writes gamma for ALL 16 rows (12 writes,
// bit-identical values -> benign write-write race), making every comb read
// ordered against the SAME wave's writes (lgkmcnt). Bonus: per-q extraction
// uses compile-time G[q], no selq. Everything else identical to R15/R12:
// feat linearized (Z = MV + vx*(wfsum-Msum)); gamma/Msum/MV/comb/beta for t+1
// in S-P2 (h-independent); S-P1 = vx(2 MFMA) + pure-register impute chain;
// G-P1 gh(6)+gi-kt0/1(6)+staging; G-P2 gi-kt2/3(6)+GRU+hbuf. 2 barriers/step,
// grid 256 (1 block/CU structural; co-residency falsified R4/R5/R7/R9).

#define Bsz 4096
#define Tn  256
#define Dn  36
#define ROWS 16
#define EPSf 1e-5f
#define VMST 38

using f32x4 = __attribute__((ext_vector_type(4))) float;
using s8    = __attribute__((ext_vector_type(8))) short;

__device__ __forceinline__ short f2bf(float x) {
  return (short)__bfloat16_as_ushort(__float2bfloat16(x));
}
__device__ __forceinline__ float sigf(float x) { return 1.f / (1.f + __expf(-x)); }
__device__ __forceinline__ float tanhfast(float x) { return 1.f - 2.f / (1.f + __expf(2.f * x)); }
// fragment-linear offset for element (row, k) of an MFMA A-tile (16 rows, bf16)
__device__ __forceinline__ int fragoff(int row, int k) {
  return ((k >> 5) << 9) + (((k >> 3) & 3) << 7) + (row << 3) + (k & 7);
}
// v[s] for wave-uniform runtime s without scratch
__device__ __forceinline__ float selq(f32x4 v, int s) {
  float a = (s & 1) ? v[1] : v[0];
  float b = (s & 1) ? v[3] : v[2];
  return (s & 2) ? b : a;
}
#define MFMA __builtin_amdgcn_mfma_f32_16x16x32_bf16

// ---------------- prepass: rmsum[t] = 1/(sum(masks[:,t,:]) + EPS) -------------
__global__ void msum_k(const float4* __restrict__ masks4, float* __restrict__ rmsum) {
  int t = blockIdx.x;
  float s = 0.f;
  for (int r = threadIdx.x; r < Bsz; r += 256) {
    const float4* mp = masks4 + ((size_t)r * Tn + t) * 9;
    #pragma unroll
    for (int j = 0; j < 9; ++j) { float4 v = mp[j]; s += v.x + v.y + v.z + v.w; }
  }
  __shared__ float red[256];
  red[threadIdx.x] = s;
  __syncthreads();
  for (int k = 128; k > 0; k >>= 1) {
    if (threadIdx.x < k) red[threadIdx.x] += red[threadIdx.x + k];
    __syncthreads();
  }
  if (threadIdx.x == 0) rmsum[t] = 1.f / (red[0] + EPSf);
}

// ---------------- main ---------------------------------------------------------
__global__ __launch_bounds__(512) void brits_main(
    const float* __restrict__ values, const float* __restrict__ masks,
    const float* __restrict__ deltas, const float* __restrict__ label,
    const float* __restrict__ is_train,
    const float* __restrict__ W_ih, const float* __restrict__ W_hh,
    const float* __restrict__ b_ih, const float* __restrict__ b_hh,
    const float* __restrict__ hist_W, const float* __restrict__ hist_b,
    const float* __restrict__ feat_W, const float* __restrict__ feat_b,
    const float* __restrict__ decay_W, const float* __restrict__ decay_b,
    const float* __restrict__ comb_W, const float* __restrict__ comb_b,
    const float* __restrict__ out_W, const float* __restrict__ out_b,
    float* __restrict__ out, const float* __restrict__ rmsum,
    float* __restrict__ ws_acc /* [0] il, [1] cls, [2] wsum */) {

  __shared__ __align__(16) float2 vm_s[2][ROWS * VMST];  // (value, mask)
  __shared__ __align__(16) short hbuf[1024];        // h bf16, K=64 frag-linear
  __shared__ __align__(16) short dbuf[2][1024];     // delta, parity-buffered
  __shared__ __align__(16) short mvbuf[2][1024];    // m*v bf16, parity-buffered
  __shared__ __align__(16) short xbuf[2][2048];     // [mask|gamma|vc2|pad] K=128
  __shared__ float red_s[512];
  __shared__ float red16[16];

  const int tid  = threadIdx.x;
  const int w    = tid >> 6;        // wave 0..7
  const int lane = tid & 63;
  const int lc   = lane & 15;
  const int r4   = lane >> 4;
  const int row0 = blockIdx.x * ROWS;
  const int k0b  = r4 * 8;
  const int lw8  = lane * 8;

  const bool isG = (w < 4);
  const int  sW  = isG ? 0 : (w - 4);
  const int  dim = 16 * (isG ? w : 0) + lc;
  const int  myrow = 4 * r4 + sW;

  // ---- role-overlaid VGPR weight fragments ----
  // G: bf[0..11] = wih (xbuf k-space remap), bf[12..17] = whh
  // S: bf[0..5]=dec, bf[6..11]=feat(zero diag), bf[12..13]=hist(all cols),
  //    bf[14..22]=comb remapped to xbuf k-space
  s8 bf[23];
  #pragma unroll
  for (int i = 0; i < 23; ++i) bf[i] = (s8)(short)0;

  if (isG) {
    #pragma unroll
    for (int g = 0; g < 3; ++g) {
      const int n = 64 * g + dim;
      #pragma unroll
      for (int kt = 0; kt < 4; ++kt) {
        s8 f;
        #pragma unroll
        for (int e = 0; e < 8; ++e) {
          int xk = k0b + 32 * kt + e;
          float wv = 0.f;
          if (xk < 72) wv = W_ih[n * 108 + 36 + xk];
          else if (xk < 108) wv = W_ih[n * 108 + xk - 72];
          f[e] = f2bf(wv);
        }
        bf[g * 4 + kt] = f;
      }
      #pragma unroll
      for (int kt = 0; kt < 2; ++kt) {
        s8 f;
        #pragma unroll
        for (int e = 0; e < 8; ++e) f[e] = f2bf(W_hh[n * 64 + k0b + 32 * kt + e]);
        bf[12 + g * 2 + kt] = f;
      }
    }
  } else {
    #pragma unroll
    for (int t3 = 0; t3 < 3; ++t3) {
      const int col = 16 * t3 + lc;
      const bool cok = (col < Dn);
      #pragma unroll
      for (int kt = 0; kt < 2; ++kt) {
        s8 fd, ff;
        #pragma unroll
        for (int e = 0; e < 8; ++e) {
          int k = k0b + 32 * kt + e;
          fd[e] = f2bf((cok && k < Dn) ? decay_W[col * Dn + k] : 0.f);
          ff[e] = f2bf((cok && k < Dn && k != col) ? feat_W[col * Dn + k] : 0.f);
        }
        bf[t3 * 2 + kt] = fd;
        bf[6 + t3 * 2 + kt] = ff;
      }
      #pragma unroll
      for (int kt = 0; kt < 3; ++kt) {
        s8 f;
        #pragma unroll
        for (int e = 0; e < 8; ++e) {
          int xk = k0b + 32 * kt + e;
          float wv = 0.f;
          if (cok) {
            if (xk < 36) wv = comb_W[col * 72 + 36 + xk];       // mask part
            else if (xk < 72) wv = comb_W[col * 72 + xk - 36];  // gamma part
          }
          f[e] = f2bf(wv);
        }
        bf[14 + t3 * 3 + kt] = f;
      }
    }
    #pragma unroll
    for (int kt = 0; kt < 2; ++kt) {
      s8 f;
      #pragma unroll
      for (int e = 0; e < 8; ++e) f[e] = f2bf(hist_W[k0b + 32 * kt + e]);
      bf[12 + kt] = f;
    }
  }

  // per-lane constants
  float db3[3] = {0,0,0}, fb3[3] = {0,0,0}, cb3[3] = {0,0,0}, wfs3[3] = {0,0,0};
  float br = 0.f, bz = 0.f, bin_ = 0.f, bhn = 0.f, ow = 0.f;
  if (isG) {
    br   = b_ih[dim] + b_hh[dim];
    bz   = b_ih[64 + dim] + b_hh[64 + dim];
    bin_ = b_ih[128 + dim];
    bhn  = b_hh[128 + dim];
    ow   = out_W[dim];
  } else {
    #pragma unroll
    for (int t3 = 0; t3 < 3; ++t3) {
      int col = 16 * t3 + lc;
      if (col < Dn) {
        db3[t3] = decay_b[col]; fb3[t3] = feat_b[col]; cb3[t3] = comb_b[col];
        float s = 0.f;
        for (int k = 0; k < Dn; ++k) if (k != col) s += feat_W[col * Dn + k];
        wfs3[t3] = s;
      }
    }
  }
  const float histb = hist_b[0];
  const int hb = fragoff(0, dim);

  // staging geometry (G waves, tids 0..143): 16 rows x 9 quads
  const bool stg = (tid < 144);
  const int srow = tid / 9;
  const int squad = tid - srow * 9;
  const size_t sbase = ((size_t)(row0 + srow) * Tn) * Dn + squad * 4;
  const int sfo = fragoff(srow, squad * 4);
  const int svo = srow * VMST + squad * 4;

  // ---- init LDS ----
  for (int i = tid; i < 1024; i += 512) {
    hbuf[i] = 0; dbuf[0][i] = 0; dbuf[1][i] = 0;
    mvbuf[0][i] = 0; mvbuf[1][i] = 0;
  }
  for (int i = tid; i < 2048; i += 512) { xbuf[0][i] = 0; xbuf[1][i] = 0; }
  __syncthreads();

  // ---- prologue: stage t=0 (parity 0), prefetch t=1 ----
  float4 pv = {0,0,0,0}, pm = {0,0,0,0}, pd = {0,0,0,0};
  if (stg) {
    float4 v0 = *(const float4*)&values[sbase];
    float4 m0 = *(const float4*)&masks[sbase];
    float4 d0 = *(const float4*)&deltas[sbase];
    *(float4*)&vm_s[0][svo]     = make_float4(v0.x, m0.x, v0.y, m0.y);
    *(float4*)&vm_s[0][svo + 2] = make_float4(v0.z, m0.z, v0.w, m0.w);
    union { short s[4]; uint2 u; } td, tm, tv;
    td.s[0]=f2bf(d0.x); td.s[1]=f2bf(d0.y); td.s[2]=f2bf(d0.z); td.s[3]=f2bf(d0.w);
    tm.s[0]=f2bf(m0.x); tm.s[1]=f2bf(m0.y); tm.s[2]=f2bf(m0.z); tm.s[3]=f2bf(m0.w);
    tv.s[0]=f2bf(m0.x*v0.x); tv.s[1]=f2bf(m0.y*v0.y);
    tv.s[2]=f2bf(m0.z*v0.z); tv.s[3]=f2bf(m0.w*v0.w);
    *(uint2*)&dbuf[0][sfo] = td.u;
    *(uint2*)&xbuf[0][sfo] = tm.u;
    *(uint2*)&mvbuf[0][sfo] = tv.u;
    pv = *(const float4*)&values[sbase + Dn];
    pm = *(const float4*)&masks[sbase + Dn];
    pd = *(const float4*)&deltas[sbase + Dn];
  }
  __syncthreads();

  float bq[3] = {0,0,0}, mvv[3] = {0,0,0}, msv[3] = {0,0,0};
  float cvv[3] = {0,0,0}, cvm[3] = {0,0,0};   // (value,mask) for CURRENT step

  // precompute lambda: Gm/gamma (ALL 16 rows, race-free), Msum/MV, comb/beta
  auto precomp = [&](const short* db_, short* xb_, const short* mv_) {
    s8 ad0 = *(const s8*)&db_[lw8];
    s8 ad1 = *(const s8*)&db_[512 + lw8];
    s8 am0 = *(const s8*)&xb_[lw8];
    s8 am1 = *(const s8*)&xb_[512 + lw8];   // stale gamma x zero weight: benign
    s8 av0 = *(const s8*)&mv_[lw8];
    s8 av1 = *(const s8*)&mv_[512 + lw8];
    f32x4 G0={0,0,0,0}, G1={0,0,0,0}, G2={0,0,0,0};
    f32x4 S0={0,0,0,0}, S1={0,0,0,0}, S2={0,0,0,0};
    f32x4 V0={0,0,0,0}, V1={0,0,0,0}, V2={0,0,0,0};
    G0 = MFMA(ad0, bf[0], G0, 0,0,0); G0 = MFMA(ad1, bf[1], G0, 0,0,0);
    G1 = MFMA(ad0, bf[2], G1, 0,0,0); G1 = MFMA(ad1, bf[3], G1, 0,0,0);
    G2 = MFMA(ad0, bf[4], G2, 0,0,0); G2 = MFMA(ad1, bf[5], G2, 0,0,0);
    S0 = MFMA(am0, bf[6], S0, 0,0,0); S0 = MFMA(am1, bf[7], S0, 0,0,0);
    S1 = MFMA(am0, bf[8], S1, 0,0,0); S1 = MFMA(am1, bf[9], S1, 0,0,0);
    S2 = MFMA(am0, bf[10], S2, 0,0,0); S2 = MFMA(am1, bf[11], S2, 0,0,0);
    V0 = MFMA(av0, bf[6], V0, 0,0,0); V0 = MFMA(av1, bf[7], V0, 0,0,0);
    V1 = MFMA(av0, bf[8], V1, 0,0,0); V1 = MFMA(av1, bf[9], V1, 0,0,0);
    V2 = MFMA(av0, bf[10], V2, 0,0,0); V2 = MFMA(av1, bf[11], V2, 0,0,0);
    // gamma for ALL 16 rows: every S wave writes identical values (benign
    // write-write race); comb reads below are ordered vs OWN writes (lgkmcnt).
    #pragma unroll
    for (int t3 = 0; t3 < 3; ++t3) {
      int col = 16 * t3 + lc;
      if (col < Dn) {
        f32x4 G = (t3 == 0) ? G0 : (t3 == 1) ? G1 : G2;
        const int gb = fragoff(0, 36 + col);
        #pragma unroll
        for (int q = 0; q < 4; ++q) {
          xb_[gb + (r4 * 4 + q) * 8] = f2bf(__expf(-fmaxf(G[q] + db3[t3], 0.f)));
        }
      }
      msv[t3] = (t3==0) ? selq(S0,sW) : (t3==1) ? selq(S1,sW) : selq(S2,sW);
      mvv[t3] = (t3==0) ? selq(V0,sW) : (t3==1) ? selq(V1,sW) : selq(V2,sW);
    }
    s8 ac1 = *(const s8*)&xb_[512 + lw8];    // re-read after own gamma writes
    s8 ac2 = *(const s8*)&xb_[1024 + lw8];
    f32x4 B0={0,0,0,0}, B1={0,0,0,0}, B2={0,0,0,0};
    B0 = MFMA(am0, bf[14], B0, 0,0,0); B0 = MFMA(ac1, bf[15], B0, 0,0,0);
    B0 = MFMA(ac2, bf[16], B0, 0,0,0);
    B1 = MFMA(am0, bf[17], B1, 0,0,0); B1 = MFMA(ac1, bf[18], B1, 0,0,0);
    B1 = MFMA(ac2, bf[19], B1, 0,0,0);
    B2 = MFMA(am0, bf[20], B2, 0,0,0); B2 = MFMA(ac1, bf[21], B2, 0,0,0);
    B2 = MFMA(ac2, bf[22], B2, 0,0,0);
    bq[0] = sigf(selq(B0,sW) + cb3[0]);
    bq[1] = sigf(selq(B1,sW) + cb3[1]);
    bq[2] = sigf(selq(B2,sW) + cb3[2]);
  };

  // S prologue for t=0
  if (!isG) {
    #pragma unroll
    for (int t3 = 0; t3 < 3; ++t3) {
      int col = 16 * t3 + lc;
      if (col < Dn) {
        float2 vm = vm_s[0][myrow * VMST + col];
        cvv[t3] = vm.x; cvm[t3] = vm.y;
      }
    }
    precomp(dbuf[0], xbuf[0], mvbuf[0]);
  }

  float hreg[4] = {0.f, 0.f, 0.f, 0.f};
  float lacc[4] = {0.f, 0.f, 0.f, 0.f};
  float il = 0.f;
  float srmv = rmsum[0];
  __syncthreads();

  #pragma unroll 2
  for (int t = 0; t < Tn; ++t) {
    const int p = t & 1;                 // folds per unrolled clone
    short* __restrict__ xb  = xbuf[p];
    short* __restrict__ xb2 = xbuf[p ^ 1];
    short* __restrict__ db2 = dbuf[p ^ 1];
    short* __restrict__ mv2 = mvbuf[p ^ 1];
    f32x4 A0 = {0,0,0,0}, A1 = {0,0,0,0}, A2 = {0,0,0,0}, A3 = {0,0,0,0};

    // ================ P1 ================
    if (isG) {
      s8 ah0 = *(const s8*)&hbuf[lw8];
      s8 ah1 = *(const s8*)&hbuf[512 + lw8];
      A0 = MFMA(ah0, bf[12], A0, 0,0,0); A0 = MFMA(ah1, bf[13], A0, 0,0,0);
      A1 = MFMA(ah0, bf[14], A1, 0,0,0); A1 = MFMA(ah1, bf[15], A1, 0,0,0);
      A3 = MFMA(ah0, bf[16], A3, 0,0,0); A3 = MFMA(ah1, bf[17], A3, 0,0,0);
      s8 ax0 = *(const s8*)&xb[lw8];
      s8 ax1 = *(const s8*)&xb[512 + lw8];
      A0 = MFMA(ax0, bf[0], A0, 0,0,0); A0 = MFMA(ax1, bf[1], A0, 0,0,0);
      A1 = MFMA(ax0, bf[4], A1, 0,0,0); A1 = MFMA(ax1, bf[5], A1, 0,0,0);
      A2 = MFMA(ax0, bf[8], A2, 0,0,0); A2 = MFMA(ax1, bf[9], A2, 0,0,0);
      // stage t+1 into parity p^1
      if (stg && t + 1 < Tn) {
        *(float4*)&vm_s[p ^ 1][svo]     = make_float4(pv.x, pm.x, pv.y, pm.y);
        *(float4*)&vm_s[p ^ 1][svo + 2] = make_float4(pv.z, pm.z, pv.w, pm.w);
        union { short s[4]; uint2 u; } td, tm, tv;
        td.s[0]=f2bf(pd.x); td.s[1]=f2bf(pd.y); td.s[2]=f2bf(pd.z); td.s[3]=f2bf(pd.w);
        tm.s[0]=f2bf(pm.x); tm.s[1]=f2bf(pm.y); tm.s[2]=f2bf(pm.z); tm.s[3]=f2bf(pm.w);
        tv.s[0]=f2bf(pm.x*pv.x); tv.s[1]=f2bf(pm.y*pv.y);
        tv.s[2]=f2bf(pm.z*pv.z); tv.s[3]=f2bf(pm.w*pv.w);
        *(uint2*)&db2[sfo] = td.u;
        *(uint2*)&xb2[sfo] = tm.u;
        *(uint2*)&mv2[sfo] = tv.u;
      }
      if (stg && t + 2 < Tn) {
        size_t o = sbase + (size_t)(t + 2) * Dn;
        pv = *(const float4*)&values[o];
        pm = *(const float4*)&masks[o];
        pd = *(const float4*)&deltas[o];
      }
    } else {
      // ---- S: h-critical chain: vx MFMA then pure register VALU ----
      s8 ah0 = *(const s8*)&hbuf[lw8];
      s8 ah1 = *(const s8*)&hbuf[512 + lw8];
      f32x4 X = {0,0,0,0};
      X = MFMA(ah0, bf[12], X, 0,0,0);
      X = MFMA(ah1, bf[13], X, 0,0,0);
      const float vx = selq(X, sW) + histb;
      #pragma unroll
      for (int t3 = 0; t3 < 3; ++t3) {
        int col = 16 * t3 + lc;
        if (col < Dn) {
          float vv = cvv[t3], mm = cvm[t3];
          float vz = vx * (wfs3[t3] - msv[t3]) + mvv[t3] + fb3[t3];
          float vh = vz * bq[t3] + vx * (1.f - bq[t3]);
          float vc2 = mm * vv + (1.f - mm) * vh;
          il += srmv * mm *
                (fabsf(vx - vv) + fabsf(vz - vv) + fabsf(vh - vv));
          out[1 + ((size_t)(row0 + myrow) * Tn + t) * Dn + col] = vc2;
          xb[fragoff(myrow, 72 + col)] = f2bf(vc2);
        }
      }
    }
    __syncthreads();  // b1: vc2 + staged t+1 visible

    // ================ P2 ================
    if (isG) {
      s8 ax2 = *(const s8*)&xb[1024 + lw8];
      s8 ax3 = *(const s8*)&xb[1536 + lw8];
      A0 = MFMA(ax2, bf[2],  A0, 0,0,0); A0 = MFMA(ax3, bf[3],  A0, 0,0,0);
      A1 = MFMA(ax2, bf[6],  A1, 0,0,0); A1 = MFMA(ax3, bf[7],  A1, 0,0,0);
      A2 = MFMA(ax2, bf[10], A2, 0,0,0); A2 = MFMA(ax3, bf[11], A2, 0,0,0);
      #pragma unroll
      for (int q = 0; q < 4; ++q) {
        float rg = sigf(A0[q] + br);
        float zg = sigf(A1[q] + bz);
        float ng = tanhfast(A2[q] + bin_ + rg * (A3[q] + bhn));
        float hn = (1.f - zg) * ng + zg * hreg[q];
        hreg[q] = hn;
        lacc[q] += hn * ow;
        hbuf[hb + (r4 * 4 + q) * 8] = f2bf(hn);
      }
    } else if (t + 1 < Tn) {
      // ---- S: precompute for t+1 (race-free gamma) + reg refills ----
      srmv = rmsum[t + 1];
      precomp(db2, xb2, mv2);
      #pragma unroll
      for (int t3 = 0; t3 < 3; ++t3) {
        int col = 16 * t3 + lc;
        if (col < Dn) {
          float2 vm = vm_s[p ^ 1][myrow * VMST + col];
          cvv[t3] = vm.x; cvm[t3] = vm.y;
        }
      }
    }
    __syncthreads();  // b2: h(t) + gamma(t+1) visible
  }

  // ---- epilogue: reduce il, logits, pred, class loss ----
  red_s[tid] = il;
  __syncthreads();
  for (int k = 256; k > 0; k >>= 1) {
    if (tid < k) red_s[tid] += red_s[tid + k];
    __syncthreads();
  }
  if (tid == 0) atomicAdd(&ws_acc[0], red_s[0]);
  if (tid < 16) red16[tid] = 0.f;
  __syncthreads();
  if (isG) {
    #pragma unroll
    for (int q = 0; q < 4; ++q) atomicAdd(&red16[r4 * 4 + q], lacc[q]);
  }
  __syncthreads();

  if (tid < ROWS) {
    float lg = red16[tid] / (float)Tn + out_b[0];
    int rg = row0 + tid;
    float pred = sigf(lg);
    out[1 + (size_t)Bsz * Tn * Dn + rg] = pred;
    float y = label[rg], wt = is_train[rg];
    float bce = fmaxf(lg, 0.f) - lg * y + log1pf(__expf(-fabsf(lg)));
    atomicAdd(&ws_acc[1], bce * wt);
    atomicAdd(&ws_acc[2], wt);
  }
}

// ---------------- finalize loss -------------------------------------------------
__global__ void fin_k(const float* __restrict__ ws, float* __restrict__ out) {
  out[0] = ws[1] / (ws[2] + EPSf) + ws[0] / (float)Tn;
}

extern "C" void kernel_launch(void* const* d_in, const int* in_sizes, int n_in,
                              void* d_out, int out_size, void* d_ws, size_t ws_size,
                              hipStream_t stream) {
  const float* values   = (const float*)d_in[0];
  const float* masks    = (const float*)d_in[1];
  const float* deltas   = (const float*)d_in[2];
  const float* label    = (const float*)d_in[3];
  const float* is_train = (const float*)d_in[4];
  const float* W_ih     = (const float*)d_in[5];
  const float* W_hh     = (const float*)d_in[6];
  const float* b_ih     = (const float*)d_in[7];
  const float* b_hh     = (const float*)d_in[8];
  const float* hist_W   = (const float*)d_in[9];
  const float* hist_b   = (const float*)d_in[10];
  const float* feat_W   = (const float*)d_in[11];
  const float* feat_b   = (const float*)d_in[12];
  const float* decay_W  = (const float*)d_in[13];
  const float* decay_b  = (const float*)d_in[14];
  const float* comb_W   = (const float*)d_in[15];
  const float* comb_b   = (const float*)d_in[16];
  const float* out_W    = (const float*)d_in[17];
  const float* out_b    = (const float*)d_in[18];

  float* ws = (float*)d_ws;
  float* rmsum = ws + 4;
  float* out = (float*)d_out;

  hipMemsetAsync(d_ws, 0, 16, stream);
  msum_k<<<Tn, 256, 0, stream>>>((const float4*)masks, rmsum);
  brits_main<<<Bsz / ROWS, 512, 0, stream>>>(
      values, masks, deltas, label, is_train, W_ih, W_hh, b_ih, b_hh,
      hist_W, hist_b, feat_W, feat_b, decay_W, decay_b, comb_W, comb_b,
      out_W, out_b, out, rmsum, ws);
  fin_k<<<1, 1, 0, stream>>>(ws, out);
}

// Round 17
// 431.395 us; speedup vs baseline: 1.1109x; 1.1109x over previous
//
#include <hip/hip_runtime.h>
#include <hip/hip_bf16.h>

// BRITS-style RNN (B=4096, T=256, D=36, H=64) on gfx950.
// R17 (final): R15 structure verbatim - the best verified kernel (432us,
// within noise of all-time best 426us R12, same structure).
// RACE ANALYSIS (corrects R16's unnecessary "fix", which cost +47us):
// In S-P2's precomp, each S-wave writes gamma only for its own rows
// {sW,4+sW,8+sW,12+sW}, then reads comb A-fragments spanning all 16 rows.
// This is race-free BY DATAFLOW: MFMA output row r depends only on A row r;
// wave sW consumes only output rows 4q+sW (selq(B,sW)) = exactly the rows
// whose gamma it wrote itself (same-wave lgkmcnt ordering). Other waves'
// A-rows (possibly stale gamma - always finite) feed only discarded rows.
// Structure: feat linearized (Z = MV + vx*(wfsum-Msum), h-independent parts
// precomputed one step ahead); S-P1 = vx(2 MFMA) + pure-register impute chain
// + f32 out store; S-P2 = Gm/gamma/Msum/MV/comb/beta for t+1 (27 MFMA) +
// (v,m)/rmsum register rotation; G-P1 = gh(6)+gi-kt0/1(6)+staging+prefetch;
// G-P2 = gi-kt2/3(6)+GRU+hbuf. 2 barriers/step, grid 256 (1 block/CU;
// co-residency falsified R4/R5/R7/R9; drain-motion falsified R13/R14).

#define Bsz 4096
#define Tn  256
#define Dn  36
#define ROWS 16
#define EPSf 1e-5f
#define VMST 38

using f32x4 = __attribute__((ext_vector_type(4))) float;
using s8    = __attribute__((ext_vector_type(8))) short;

__device__ __forceinline__ short f2bf(float x) {
  return (short)__bfloat16_as_ushort(__float2bfloat16(x));
}
__device__ __forceinline__ float sigf(float x) { return 1.f / (1.f + __expf(-x)); }
__device__ __forceinline__ float tanhfast(float x) { return 1.f - 2.f / (1.f + __expf(2.f * x)); }
// fragment-linear offset for element (row, k) of an MFMA A-tile (16 rows, bf16)
__device__ __forceinline__ int fragoff(int row, int k) {
  return ((k >> 5) << 9) + (((k >> 3) & 3) << 7) + (row << 3) + (k & 7);
}
// v[s] for wave-uniform runtime s without scratch
__device__ __forceinline__ float selq(f32x4 v, int s) {
  float a = (s & 1) ? v[1] : v[0];
  float b = (s & 1) ? v[3] : v[2];
  return (s & 2) ? b : a;
}
#define MFMA __builtin_amdgcn_mfma_f32_16x16x32_bf16

// ---------------- prepass: rmsum[t] = 1/(sum(masks[:,t,:]) + EPS) -------------
__global__ void msum_k(const float4* __restrict__ masks4, float* __restrict__ rmsum) {
  int t = blockIdx.x;
  float s = 0.f;
  for (int r = threadIdx.x; r < Bsz; r += 256) {
    const float4* mp = masks4 + ((size_t)r * Tn + t) * 9;
    #pragma unroll
    for (int j = 0; j < 9; ++j) { float4 v = mp[j]; s += v.x + v.y + v.z + v.w; }
  }
  __shared__ float red[256];
  red[threadIdx.x] = s;
  __syncthreads();
  for (int k = 128; k > 0; k >>= 1) {
    if (threadIdx.x < k) red[threadIdx.x] += red[threadIdx.x + k];
    __syncthreads();
  }
  if (threadIdx.x == 0) rmsum[t] = 1.f / (red[0] + EPSf);
}

// ---------------- main ---------------------------------------------------------
__global__ __launch_bounds__(512) void brits_main(
    const float* __restrict__ values, const float* __restrict__ masks,
    const float* __restrict__ deltas, const float* __restrict__ label,
    const float* __restrict__ is_train,
    const float* __restrict__ W_ih, const float* __restrict__ W_hh,
    const float* __restrict__ b_ih, const float* __restrict__ b_hh,
    const float* __restrict__ hist_W, const float* __restrict__ hist_b,
    const float* __restrict__ feat_W, const float* __restrict__ feat_b,
    const float* __restrict__ decay_W, const float* __restrict__ decay_b,
    const float* __restrict__ comb_W, const float* __restrict__ comb_b,
    const float* __restrict__ out_W, const float* __restrict__ out_b,
    float* __restrict__ out, const float* __restrict__ rmsum,
    float* __restrict__ ws_acc /* [0] il, [1] cls, [2] wsum */) {

  __shared__ __align__(16) float2 vm_s[2][ROWS * VMST];  // (value, mask)
  __shared__ __align__(16) short hbuf[1024];        // h bf16, K=64 frag-linear
  __shared__ __align__(16) short dbuf[2][1024];     // delta, parity-buffered
  __shared__ __align__(16) short mvbuf[2][1024];    // m*v bf16, parity-buffered
  __shared__ __align__(16) short xbuf[2][2048];     // [mask|gamma|vc2|pad] K=128
  __shared__ float red_s[512];
  __shared__ float red16[16];

  const int tid  = threadIdx.x;
  const int w    = tid >> 6;        // wave 0..7
  const int lane = tid & 63;
  const int lc   = lane & 15;
  const int r4   = lane >> 4;
  const int row0 = blockIdx.x * ROWS;
  const int k0b  = r4 * 8;
  const int lw8  = lane * 8;

  const bool isG = (w < 4);
  const int  sW  = isG ? 0 : (w - 4);
  const int  dim = 16 * (isG ? w : 0) + lc;
  const int  myrow = 4 * r4 + sW;

  // ---- role-overlaid VGPR weight fragments ----
  // G: bf[0..11] = wih (xbuf k-space remap), bf[12..17] = whh
  // S: bf[0..5]=dec, bf[6..11]=feat(zero diag), bf[12..13]=hist(all cols),
  //    bf[14..22]=comb remapped to xbuf k-space
  s8 bf[23];
  #pragma unroll
  for (int i = 0; i < 23; ++i) bf[i] = (s8)(short)0;

  if (isG) {
    #pragma unroll
    for (int g = 0; g < 3; ++g) {
      const int n = 64 * g + dim;
      #pragma unroll
      for (int kt = 0; kt < 4; ++kt) {
        s8 f;
        #pragma unroll
        for (int e = 0; e < 8; ++e) {
          int xk = k0b + 32 * kt + e;
          float wv = 0.f;
          if (xk < 72) wv = W_ih[n * 108 + 36 + xk];
          else if (xk < 108) wv = W_ih[n * 108 + xk - 72];
          f[e] = f2bf(wv);
        }
        bf[g * 4 + kt] = f;
      }
      #pragma unroll
      for (int kt = 0; kt < 2; ++kt) {
        s8 f;
        #pragma unroll
        for (int e = 0; e < 8; ++e) f[e] = f2bf(W_hh[n * 64 + k0b + 32 * kt + e]);
        bf[12 + g * 2 + kt] = f;
      }
    }
  } else {
    #pragma unroll
    for (int t3 = 0; t3 < 3; ++t3) {
      const int col = 16 * t3 + lc;
      const bool cok = (col < Dn);
      #pragma unroll
      for (int kt = 0; kt < 2; ++kt) {
        s8 fd, ff;
        #pragma unroll
        for (int e = 0; e < 8; ++e) {
          int k = k0b + 32 * kt + e;
          fd[e] = f2bf((cok && k < Dn) ? decay_W[col * Dn + k] : 0.f);
          ff[e] = f2bf((cok && k < Dn && k != col) ? feat_W[col * Dn + k] : 0.f);
        }
        bf[t3 * 2 + kt] = fd;
        bf[6 + t3 * 2 + kt] = ff;
      }
      #pragma unroll
      for (int kt = 0; kt < 3; ++kt) {
        s8 f;
        #pragma unroll
        for (int e = 0; e < 8; ++e) {
          int xk = k0b + 32 * kt + e;
          float wv = 0.f;
          if (cok) {
            if (xk < 36) wv = comb_W[col * 72 + 36 + xk];       // mask part
            else if (xk < 72) wv = comb_W[col * 72 + xk - 36];  // gamma part
          }
          f[e] = f2bf(wv);
        }
        bf[14 + t3 * 3 + kt] = f;
      }
    }
    #pragma unroll
    for (int kt = 0; kt < 2; ++kt) {
      s8 f;
      #pragma unroll
      for (int e = 0; e < 8; ++e) f[e] = f2bf(hist_W[k0b + 32 * kt + e]);
      bf[12 + kt] = f;
    }
  }

  // per-lane constants
  float db3[3] = {0,0,0}, fb3[3] = {0,0,0}, cb3[3] = {0,0,0}, wfs3[3] = {0,0,0};
  float br = 0.f, bz = 0.f, bin_ = 0.f, bhn = 0.f, ow = 0.f;
  if (isG) {
    br   = b_ih[dim] + b_hh[dim];
    bz   = b_ih[64 + dim] + b_hh[64 + dim];
    bin_ = b_ih[128 + dim];
    bhn  = b_hh[128 + dim];
    ow   = out_W[dim];
  } else {
    #pragma unroll
    for (int t3 = 0; t3 < 3; ++t3) {
      int col = 16 * t3 + lc;
      if (col < Dn) {
        db3[t3] = decay_b[col]; fb3[t3] = feat_b[col]; cb3[t3] = comb_b[col];
        float s = 0.f;
        for (int k = 0; k < Dn; ++k) if (k != col) s += feat_W[col * Dn + k];
        wfs3[t3] = s;
      }
    }
  }
  const float histb = hist_b[0];
  const int hb = fragoff(0, dim);

  // staging geometry (G waves, tids 0..143): 16 rows x 9 quads
  const bool stg = (tid < 144);
  const int srow = tid / 9;
  const int squad = tid - srow * 9;
  const size_t sbase = ((size_t)(row0 + srow) * Tn) * Dn + squad * 4;
  const int sfo = fragoff(srow, squad * 4);
  const int svo = srow * VMST + squad * 4;

  // ---- init LDS ----
  for (int i = tid; i < 1024; i += 512) {
    hbuf[i] = 0; dbuf[0][i] = 0; dbuf[1][i] = 0;
    mvbuf[0][i] = 0; mvbuf[1][i] = 0;
  }
  for (int i = tid; i < 2048; i += 512) { xbuf[0][i] = 0; xbuf[1][i] = 0; }
  __syncthreads();

  // ---- prologue: stage t=0 (parity 0), prefetch t=1 ----
  float4 pv = {0,0,0,0}, pm = {0,0,0,0}, pd = {0,0,0,0};
  if (stg) {
    float4 v0 = *(const float4*)&values[sbase];
    float4 m0 = *(const float4*)&masks[sbase];
    float4 d0 = *(const float4*)&deltas[sbase];
    *(float4*)&vm_s[0][svo]     = make_float4(v0.x, m0.x, v0.y, m0.y);
    *(float4*)&vm_s[0][svo + 2] = make_float4(v0.z, m0.z, v0.w, m0.w);
    union { short s[4]; uint2 u; } td, tm, tv;
    td.s[0]=f2bf(d0.x); td.s[1]=f2bf(d0.y); td.s[2]=f2bf(d0.z); td.s[3]=f2bf(d0.w);
    tm.s[0]=f2bf(m0.x); tm.s[1]=f2bf(m0.y); tm.s[2]=f2bf(m0.z); tm.s[3]=f2bf(m0.w);
    tv.s[0]=f2bf(m0.x*v0.x); tv.s[1]=f2bf(m0.y*v0.y);
    tv.s[2]=f2bf(m0.z*v0.z); tv.s[3]=f2bf(m0.w*v0.w);
    *(uint2*)&dbuf[0][sfo] = td.u;
    *(uint2*)&xbuf[0][sfo] = tm.u;
    *(uint2*)&mvbuf[0][sfo] = tv.u;
    pv = *(const float4*)&values[sbase + Dn];
    pm = *(const float4*)&masks[sbase + Dn];
    pd = *(const float4*)&deltas[sbase + Dn];
  }
  __syncthreads();

  float bq[3] = {0,0,0}, mvv[3] = {0,0,0}, msv[3] = {0,0,0};
  float cvv[3] = {0,0,0}, cvm[3] = {0,0,0};   // (value,mask) for CURRENT step
  // S prologue for t=0: Gm/gamma -> xbuf[0]; Msum/MV; comb/beta; v,m -> regs
  if (!isG) {
    #pragma unroll
    for (int t3 = 0; t3 < 3; ++t3) {
      int col = 16 * t3 + lc;
      if (col < Dn) {
        float2 vm = vm_s[0][myrow * VMST + col];
        cvv[t3] = vm.x; cvm[t3] = vm.y;
      }
    }
    s8 ad0 = *(const s8*)&dbuf[0][lw8];
    s8 ad1 = *(const s8*)&dbuf[0][512 + lw8];
    s8 am0 = *(const s8*)&xbuf[0][lw8];
    s8 am1 = *(const s8*)&xbuf[0][512 + lw8];
    s8 av0 = *(const s8*)&mvbuf[0][lw8];
    s8 av1 = *(const s8*)&mvbuf[0][512 + lw8];
    f32x4 G0={0,0,0,0}, G1={0,0,0,0}, G2={0,0,0,0};
    f32x4 S0={0,0,0,0}, S1={0,0,0,0}, S2={0,0,0,0};
    f32x4 V0={0,0,0,0}, V1={0,0,0,0}, V2={0,0,0,0};
    G0 = MFMA(ad0, bf[0], G0, 0,0,0); G0 = MFMA(ad1, bf[1], G0, 0,0,0);
    G1 = MFMA(ad0, bf[2], G1, 0,0,0); G1 = MFMA(ad1, bf[3], G1, 0,0,0);
    G2 = MFMA(ad0, bf[4], G2, 0,0,0); G2 = MFMA(ad1, bf[5], G2, 0,0,0);
    S0 = MFMA(am0, bf[6], S0, 0,0,0); S0 = MFMA(am1, bf[7], S0, 0,0,0);
    S1 = MFMA(am0, bf[8], S1, 0,0,0); S1 = MFMA(am1, bf[9], S1, 0,0,0);
    S2 = MFMA(am0, bf[10], S2, 0,0,0); S2 = MFMA(am1, bf[11], S2, 0,0,0);
    V0 = MFMA(av0, bf[6], V0, 0,0,0); V0 = MFMA(av1, bf[7], V0, 0,0,0);
    V1 = MFMA(av0, bf[8], V1, 0,0,0); V1 = MFMA(av1, bf[9], V1, 0,0,0);
    V2 = MFMA(av0, bf[10], V2, 0,0,0); V2 = MFMA(av1, bf[11], V2, 0,0,0);
    #pragma unroll
    for (int t3 = 0; t3 < 3; ++t3) {
      int col = 16 * t3 + lc;
      if (col < Dn) {
        float gm = (t3==0) ? selq(G0,sW) : (t3==1) ? selq(G1,sW) : selq(G2,sW);
        xbuf[0][fragoff(myrow, 36 + col)] = f2bf(__expf(-fmaxf(gm + db3[t3], 0.f)));
      }
      msv[t3] = (t3==0) ? selq(S0,sW) : (t3==1) ? selq(S1,sW) : selq(S2,sW);
      mvv[t3] = (t3==0) ? selq(V0,sW) : (t3==1) ? selq(V1,sW) : selq(V2,sW);
    }
    s8 ac1 = *(const s8*)&xbuf[0][512 + lw8];
    s8 ac2 = *(const s8*)&xbuf[0][1024 + lw8];
    f32x4 B0={0,0,0,0}, B1={0,0,0,0}, B2={0,0,0,0};
    B0 = MFMA(am0, bf[14], B0, 0,0,0); B0 = MFMA(ac1, bf[15], B0, 0,0,0);
    B0 = MFMA(ac2, bf[16], B0, 0,0,0);
    B1 = MFMA(am0, bf[17], B1, 0,0,0); B1 = MFMA(ac1, bf[18], B1, 0,0,0);
    B1 = MFMA(ac2, bf[19], B1, 0,0,0);
    B2 = MFMA(am0, bf[20], B2, 0,0,0); B2 = MFMA(ac1, bf[21], B2, 0,0,0);
    B2 = MFMA(ac2, bf[22], B2, 0,0,0);
    bq[0] = sigf(selq(B0,sW) + cb3[0]);
    bq[1] = sigf(selq(B1,sW) + cb3[1]);
    bq[2] = sigf(selq(B2,sW) + cb3[2]);
  }

  float hreg[4] = {0.f, 0.f, 0.f, 0.f};
  float lacc[4] = {0.f, 0.f, 0.f, 0.f};
  float il = 0.f;
  float srmv = rmsum[0];
  __syncthreads();

  #pragma unroll 2
  for (int t = 0; t < Tn; ++t) {
    const int p = t & 1;                 // folds per unrolled clone
    short* __restrict__ xb  = xbuf[p];
    short* __restrict__ xb2 = xbuf[p ^ 1];
    short* __restrict__ db2 = dbuf[p ^ 1];
    short* __restrict__ mv2 = mvbuf[p ^ 1];
    f32x4 A0 = {0,0,0,0}, A1 = {0,0,0,0}, A2 = {0,0,0,0}, A3 = {0,0,0,0};

    // ================ P1 ================
    if (isG) {
      s8 ah0 = *(const s8*)&hbuf[lw8];
      s8 ah1 = *(const s8*)&hbuf[512 + lw8];
      A0 = MFMA(ah0, bf[12], A0, 0,0,0); A0 = MFMA(ah1, bf[13], A0, 0,0,0);
      A1 = MFMA(ah0, bf[14], A1, 0,0,0); A1 = MFMA(ah1, bf[15], A1, 0,0,0);
      A3 = MFMA(ah0, bf[16], A3, 0,0,0); A3 = MFMA(ah1, bf[17], A3, 0,0,0);
      s8 ax0 = *(const s8*)&xb[lw8];
      s8 ax1 = *(const s8*)&xb[512 + lw8];
      A0 = MFMA(ax0, bf[0], A0, 0,0,0); A0 = MFMA(ax1, bf[1], A0, 0,0,0);
      A1 = MFMA(ax0, bf[4], A1, 0,0,0); A1 = MFMA(ax1, bf[5], A1, 0,0,0);
      A2 = MFMA(ax0, bf[8], A2, 0,0,0); A2 = MFMA(ax1, bf[9], A2, 0,0,0);
      // stage t+1 into parity p^1
      if (stg && t + 1 < Tn) {
        *(float4*)&vm_s[p ^ 1][svo]     = make_float4(pv.x, pm.x, pv.y, pm.y);
        *(float4*)&vm_s[p ^ 1][svo + 2] = make_float4(pv.z, pm.z, pv.w, pm.w);
        union { short s[4]; uint2 u; } td, tm, tv;
        td.s[0]=f2bf(pd.x); td.s[1]=f2bf(pd.y); td.s[2]=f2bf(pd.z); td.s[3]=f2bf(pd.w);
        tm.s[0]=f2bf(pm.x); tm.s[1]=f2bf(pm.y); tm.s[2]=f2bf(pm.z); tm.s[3]=f2bf(pm.w);
        tv.s[0]=f2bf(pm.x*pv.x); tv.s[1]=f2bf(pm.y*pv.y);
        tv.s[2]=f2bf(pm.z*pv.z); tv.s[3]=f2bf(pm.w*pv.w);
        *(uint2*)&db2[sfo] = td.u;
        *(uint2*)&xb2[sfo] = tm.u;
        *(uint2*)&mv2[sfo] = tv.u;
      }
      if (stg && t + 2 < Tn) {
        size_t o = sbase + (size_t)(t + 2) * Dn;
        pv = *(const float4*)&values[o];
        pm = *(const float4*)&masks[o];
        pd = *(const float4*)&deltas[o];
      }
    } else {
      // ---- S: h-critical chain: vx MFMA then pure register VALU ----
      s8 ah0 = *(const s8*)&hbuf[lw8];
      s8 ah1 = *(const s8*)&hbuf[512 + lw8];
      f32x4 X = {0,0,0,0};
      X = MFMA(ah0, bf[12], X, 0,0,0);
      X = MFMA(ah1, bf[13], X, 0,0,0);
      const float vx = selq(X, sW) + histb;
      #pragma unroll
      for (int t3 = 0; t3 < 3; ++t3) {
        int col = 16 * t3 + lc;
        if (col < Dn) {
          float vv = cvv[t3], mm = cvm[t3];
          float vz = vx * (wfs3[t3] - msv[t3]) + mvv[t3] + fb3[t3];
          float vh = vz * bq[t3] + vx * (1.f - bq[t3]);
          float vc2 = mm * vv + (1.f - mm) * vh;
          il += srmv * mm *
                (fabsf(vx - vv) + fabsf(vz - vv) + fabsf(vh - vv));
          out[1 + ((size_t)(row0 + myrow) * Tn + t) * Dn + col] = vc2;
          xb[fragoff(myrow, 72 + col)] = f2bf(vc2);
        }
      }
    }
    __syncthreads();  // b1: vc2 + staged t+1 visible

    // ================ P2 ================
    if (isG) {
      s8 ax2 = *(const s8*)&xb[1024 + lw8];
      s8 ax3 = *(const s8*)&xb[1536 + lw8];
      A0 = MFMA(ax2, bf[2],  A0, 0,0,0); A0 = MFMA(ax3, bf[3],  A0, 0,0,0);
      A1 = MFMA(ax2, bf[6],  A1, 0,0,0); A1 = MFMA(ax3, bf[7],  A1, 0,0,0);
      A2 = MFMA(ax2, bf[10], A2, 0,0,0); A2 = MFMA(ax3, bf[11], A2, 0,0,0);
      #pragma unroll
      for (int q = 0; q < 4; ++q) {
        float rg = sigf(A0[q] + br);
        float zg = sigf(A1[q] + bz);
        float ng = tanhfast(A2[q] + bin_ + rg * (A3[q] + bhn));
        float hn = (1.f - zg) * ng + zg * hreg[q];
        hreg[q] = hn;
        lacc[q] += hn * ow;
        hbuf[hb + (r4 * 4 + q) * 8] = f2bf(hn);
      }
    } else if (t + 1 < Tn) {
      // ---- S: precompute for t+1: Gm/gamma, Msum, MV, comb/beta; regs ----
      srmv = rmsum[t + 1];
      s8 ad0 = *(const s8*)&db2[lw8];
      s8 ad1 = *(const s8*)&db2[512 + lw8];
      s8 am0 = *(const s8*)&xb2[lw8];
      s8 am1 = *(const s8*)&xb2[512 + lw8];   // stale gamma x zero weight: benign
      s8 av0 = *(const s8*)&mv2[lw8];
      s8 av1 = *(const s8*)&mv2[512 + lw8];
      f32x4 G0={0,0,0,0}, G1={0,0,0,0}, G2={0,0,0,0};
      f32x4 S0={0,0,0,0}, S1={0,0,0,0}, S2={0,0,0,0};
      f32x4 V0={0,0,0,0}, V1={0,0,0,0}, V2={0,0,0,0};
      G0 = MFMA(ad0, bf[0], G0, 0,0,0); G0 = MFMA(ad1, bf[1], G0, 0,0,0);
      G1 = MFMA(ad0, bf[2], G1, 0,0,0); G1 = MFMA(ad1, bf[3], G1, 0,0,0);
      G2 = MFMA(ad0, bf[4], G2, 0,0,0); G2 = MFMA(ad1, bf[5], G2, 0,0,0);
      S0 = MFMA(am0, bf[6], S0, 0,0,0); S0 = MFMA(am1, bf[7], S0, 0,0,0);
      S1 = MFMA(am0, bf[8], S1, 0,0,0); S1 = MFMA(am1, bf[9], S1, 0,0,0);
      S2 = MFMA(am0, bf[10], S2, 0,0,0); S2 = MFMA(am1, bf[11], S2, 0,0,0);
      V0 = MFMA(av0, bf[6], V0, 0,0,0); V0 = MFMA(av1, bf[7], V0, 0,0,0);
      V1 = MFMA(av0, bf[8], V1, 0,0,0); V1 = MFMA(av1, bf[9], V1, 0,0,0);
      V2 = MFMA(av0, bf[10], V2, 0,0,0); V2 = MFMA(av1, bf[11], V2, 0,0,0);
      #pragma unroll
      for (int t3 = 0; t3 < 3; ++t3) {
        int col = 16 * t3 + lc;
        if (col < Dn) {
          float gm = (t3==0) ? selq(G0,sW) : (t3==1) ? selq(G1,sW) : selq(G2,sW);
          xb2[fragoff(myrow, 36 + col)] = f2bf(__expf(-fmaxf(gm + db3[t3], 0.f)));
        }
        msv[t3] = (t3==0) ? selq(S0,sW) : (t3==1) ? selq(S1,sW) : selq(S2,sW);
        mvv[t3] = (t3==0) ? selq(V0,sW) : (t3==1) ? selq(V1,sW) : selq(V2,sW);
      }
      s8 ac1 = *(const s8*)&xb2[512 + lw8];
      s8 ac2 = *(const s8*)&xb2[1024 + lw8];
      f32x4 B0={0,0,0,0}, B1={0,0,0,0}, B2={0,0,0,0};
      B0 = MFMA(am0, bf[14], B0, 0,0,0); B0 = MFMA(ac1, bf[15], B0, 0,0,0);
      B0 = MFMA(ac2, bf[16], B0, 0,0,0);
      B1 = MFMA(am0, bf[17], B1, 0,0,0); B1 = MFMA(ac1, bf[18], B1, 0,0,0);
      B1 = MFMA(ac2, bf[19], B1, 0,0,0);
      B2 = MFMA(am0, bf[20], B2, 0,0,0); B2 = MFMA(ac1, bf[21], B2, 0,0,0);
      B2 = MFMA(ac2, bf[22], B2, 0,0,0);
      bq[0] = sigf(selq(B0,sW) + cb3[0]);
      bq[1] = sigf(selq(B1,sW) + cb3[1]);
      bq[2] = sigf(selq(B2,sW) + cb3[2]);
      // refill (value,mask) regs for step t+1 from vm_s[p^1] (staged in G-P1)
      #pragma unroll
      for (int t3 = 0; t3 < 3; ++t3) {
        int col = 16 * t3 + lc;
        if (col < Dn) {
          float2 vm = vm_s[p ^ 1][myrow * VMST + col];
          cvv[t3] = vm.x; cvm[t3] = vm.y;
        }
      }
    }
    __syncthreads();  // b2: h(t) + gamma(t+1) visible
  }

  // ---- epilogue: reduce il, logits, pred, class loss ----
  red_s[tid] = il;
  __syncthreads();
  for (int k = 256; k > 0; k >>= 1) {
    if (tid < k) red_s[tid] += red_s[tid + k];
    __syncthreads();
  }
  if (tid == 0) atomicAdd(&ws_acc[0], red_s[0]);
  if (tid < 16) red16[tid] = 0.f;
  __syncthreads();
  if (isG) {
    #pragma unroll
    for (int q = 0; q < 4; ++q) atomicAdd(&red16[r4 * 4 + q], lacc[q]);
  }
  __syncthreads();

  if (tid < ROWS) {
    float lg = red16[tid] / (float)Tn + out_b[0];
    int rg = row0 + tid;
    float pred = sigf(lg);
    out[1 + (size_t)Bsz * Tn * Dn + rg] = pred;
    float y = label[rg], wt = is_train[rg];
    float bce = fmaxf(lg, 0.f) - lg * y + log1pf(__expf(-fabsf(lg)));
    atomicAdd(&ws_acc[1], bce * wt);
    atomicAdd(&ws_acc[2], wt);
  }
}

// ---------------- finalize loss -------------------------------------------------
__global__ void fin_k(const float* __restrict__ ws, float* __restrict__ out) {
  out[0] = ws[1] / (ws[2] + EPSf) + ws[0] / (float)Tn;
}

extern "C" void kernel_launch(void* const* d_in, const int* in_sizes, int n_in,
                              void* d_out, int out_size, void* d_ws, size_t ws_size,
                              hipStream_t stream) {
  const float* values   = (const float*)d_in[0];
  const float* masks    = (const float*)d_in[1];
  const float* deltas   = (const float*)d_in[2];
  const float* label    = (const float*)d_in[3];
  const float* is_train = (const float*)d_in[4];
  const float* W_ih     = (const float*)d_in[5];
  const float* W_hh     = (const float*)d_in[6];
  const float* b_ih     = (const float*)d_in[7];
  const float* b_hh     = (const float*)d_in[8];
  const float* hist_W   = (const float*)d_in[9];
  const float* hist_b   = (const float*)d_in[10];
  const float* feat_W   = (const float*)d_in[11];
  const float* feat_b   = (const float*)d_in[12];
  const float* decay_W  = (const float*)d_in[13];
  const float* decay_b  = (const float*)d_in[14];
  const float* comb_W   = (const float*)d_in[15];
  const float* comb_b   = (const float*)d_in[16];
  const float* out_W    = (const float*)d_in[17];
  const float* out_b    = (const float*)d_in[18];

  float* ws = (float*)d_ws;
  float* rmsum = ws + 4;
  float* out = (float*)d_out;

  hipMemsetAsync(d_ws, 0, 16, stream);
  msum_k<<<Tn, 256, 0, stream>>>((const float4*)masks, rmsum);
  brits_main<<<Bsz / ROWS, 512, 0, stream>>>(
      values, masks, deltas, label, is_train, W_ih, W_hh, b_ih, b_hh,
      hist_W, hist_b, feat_W, feat_b, decay_W, decay_b, comb_W, comb_b,
      out_W, out_b, out, rmsum, ws);
  fin_k<<<1, 1, 0, stream>>>(ws, out);
}